// Round 9
// baseline (21757.883 us; speedup 1.0000x reference)
//
#include <hip/hip_runtime.h>

using short8 = __attribute__((ext_vector_type(8))) short;
using f32x4  = __attribute__((ext_vector_type(4))) float;

#define NN 4096
#define TT 365
#define DD 16
#define HH 256
#define PP 2
#define TD (TT*DD)      // 5840
#define TP (TT*PP)      // 730
#define KG 320          // gates K: [h(256) | x(16) | pad(48)]
#define ASCALE 4096.0f
#define HWSCALE 64.0f
#define AINV2 (1.0f/(4096.0f*64.0f))   // A8 scale * hwT8 scale

__device__ __forceinline__ unsigned short f2bf(float f) {
    union { float f; unsigned u; } v; v.f = f;
    unsigned r = v.u + 0x7FFFu + ((v.u >> 16) & 1u);   // RNE
    return (unsigned short)(r >> 16);
}
// float -> OCP e4m3fn, RNE, saturating at 448
__device__ __forceinline__ unsigned char f2e4m3(float f) {
    union { float f; unsigned u; } v; v.f = f;
    unsigned s = (v.u >> 24) & 0x80u;
    unsigned au = v.u & 0x7fffffffu;
    if (au >= 0x43E00000u) return (unsigned char)(s | 0x7E);   // >=448 -> 448
    if (au < 0x3C800000u) {                                    // <2^-6: subnormal
        int m = __float2int_rn(__uint_as_float(au) * 512.0f);  // 0..8
        return (unsigned char)(s | (unsigned)m);
    }
    unsigned r = au + 0x7FFFFu + ((au >> 20) & 1u);            // RNE to 3 mantissa bits
    return (unsigned char)(s | ((r >> 20) - 0x3C0u));
}
__device__ __forceinline__ float sigmoidf_(float x) {
    return 1.0f / (1.0f + __expf(-x));
}
__device__ __forceinline__ float tanhf_(float x) {
    float t = __expf(2.0f * x);
    return (t - 1.0f) / (t + 1.0f);
}
__device__ __forceinline__ void async16(const void* g, void* l) {
    __builtin_amdgcn_global_load_lds(
        (const __attribute__((address_space(1))) void*)g,
        (__attribute__((address_space(3))) void*)l, 16, 0, 0);
}

// ---------------------------------------------------------------------------
// bf16 core, double-buffered with COUNTED vmcnt (T4): 256 thr = 4 waves 2x2.
// BN=128, BK=64, BM=32*TI. C = Amat(row,lda) @ Bt^T (Bt[col][k],ldb).
// ---------------------------------------------------------------------------
template<int TI>
__device__ __forceinline__ void gemm_core_db(
    const unsigned short* __restrict__ Amat, int lda,
    const unsigned short* __restrict__ Bt,  int ldb,
    int k_len, int row0, int col0,
    unsigned short* As, unsigned short* Bs,
    f32x4 (&acc)[TI][4])
{
    const int tid  = threadIdx.x;
    const int lane = tid & 63;
    const int wave = tid >> 6;
    const int srow = lane >> 3;
    const int sblk = lane & 7;
    const int ABUF = TI * 32 * 64;     // shorts per A buffer
    const int BBUF = 128 * 64;         // shorts per B buffer

    const unsigned short* Ag = Amat + (size_t)(row0 + wave*8 + srow) * lda
                                    + ((sblk ^ srow) * 8);
    const unsigned short* Bg = Bt   + (size_t)(col0 + wave*8 + srow) * ldb
                                    + ((sblk ^ srow) * 8);

    const int fr = lane & 15;
    const int fq = lane >> 4;
    const int wr = (wave >> 1) * (TI * 16);
    const int wc = (wave & 1) * 64;
    const int off0 = ((fq ^ (fr & 7)) * 8);

    {   // prologue: tile 0 -> buffer 0
        unsigned short* AsW = As + wave * 512;
        unsigned short* BsW = Bs + wave * 512;
        #pragma unroll
        for (int q = 0; q < TI; q++) async16(Ag + (size_t)q * 32 * lda, AsW + q * 2048);
        #pragma unroll
        for (int q = 0; q < 4;  q++) async16(Bg + (size_t)q * 32 * ldb, BsW + q * 2048);
    }

    const int nk = k_len >> 6;
    int sel = 0;
    for (int it = 0; it < nk; ++it) {
        if (it + 1 < nk) {
            const unsigned short* Agn = Ag + (it + 1) * 64;
            const unsigned short* Bgn = Bg + (it + 1) * 64;
            unsigned short* AsW = As + (sel ^ 1) * ABUF + wave * 512;
            unsigned short* BsW = Bs + (sel ^ 1) * BBUF + wave * 512;
            #pragma unroll
            for (int q = 0; q < TI; q++) async16(Agn + (size_t)q * 32 * lda, AsW + q * 2048);
            #pragma unroll
            for (int q = 0; q < 4;  q++) async16(Bgn + (size_t)q * 32 * ldb, BsW + q * 2048);
            if constexpr (TI == 4)      asm volatile("s_waitcnt vmcnt(8)" ::: "memory");
            else if constexpr (TI == 2) asm volatile("s_waitcnt vmcnt(6)" ::: "memory");
            else                        asm volatile("s_waitcnt vmcnt(0)" ::: "memory");
        } else {
            asm volatile("s_waitcnt vmcnt(0)" ::: "memory");
        }
        __builtin_amdgcn_s_barrier();          // all waves: tile(it) landed
        __builtin_amdgcn_sched_barrier(0);
        const unsigned short* Ab = As + sel * ABUF;
        const unsigned short* Bb = Bs + sel * BBUF;
        #pragma unroll
        for (int kh = 0; kh < 2; kh++) {
            const int off = off0 ^ (kh * 32);
            short8 a[TI], b[4];
            #pragma unroll
            for (int i = 0; i < TI; i++)
                a[i] = *(const short8*)(Ab + (wr + i*16 + fr) * 64 + off);
            #pragma unroll
            for (int j = 0; j < 4;  j++)
                b[j] = *(const short8*)(Bb + (wc + j*16 + fr) * 64 + off);
            #pragma unroll
            for (int i = 0; i < TI; i++)
                #pragma unroll
                for (int j = 0; j < 4; j++)
                    acc[i][j] = __builtin_amdgcn_mfma_f32_16x16x32_bf16(
                        a[i], b[j], acc[i][j], 0, 0, 0);
        }
        __builtin_amdgcn_s_barrier();          // reads of buf[sel] done
        sel ^= 1;
    }
}

// ---------------------------------------------------------------------------
// fp8 core, double-buffered with COUNTED vmcnt, BM=32*TI x 128 tile:
// C = A8 @ B8^T, both row-major [*][NN] bytes, BK=128.
// ---------------------------------------------------------------------------
template<int TI>
__device__ __forceinline__ void gemm8_db(
    const unsigned char* __restrict__ Amat,
    const unsigned char* __restrict__ Bmat,
    int kb, int klen, int row0, int col0,
    unsigned char* As, unsigned char* Bs,
    f32x4 (&acc)[TI][4])
{
    const int tid  = threadIdx.x;
    const int lane = tid & 63;
    const int wave = tid >> 6;
    const int srow = lane >> 3;
    const int sblk = lane & 7;
    const int ABUF = TI * 32 * 128;
    const int BBUF = 128 * 128;

    const unsigned char* Ag = Amat + (size_t)(row0 + wave*8 + srow) * NN
                                   + ((sblk ^ srow) * 16) + kb;
    const unsigned char* Bg = Bmat + (size_t)(col0 + wave*8 + srow) * NN
                                   + ((sblk ^ srow) * 16) + kb;

    const int fr = lane & 15;
    const int fq = lane >> 4;
    const int wr = (wave >> 1) * (TI * 16);
    const int wc = (wave & 1) * 64;
    int offk[4];
    #pragma unroll
    for (int kq = 0; kq < 4; kq++)
        offk[kq] = (((kq*2 + (fq >> 1)) ^ (fr & 7)) << 4) + ((fq & 1) << 3);

    {   // prologue
        unsigned char* AsW = As + wave * 1024;
        unsigned char* BsW = Bs + wave * 1024;
        #pragma unroll
        for (int q = 0; q < TI; q++) async16(Ag + (size_t)q * 32 * NN, AsW + q * 4096);
        #pragma unroll
        for (int q = 0; q < 4;  q++) async16(Bg + (size_t)q * 32 * NN, BsW + q * 4096);
    }

    const int nk = klen >> 7;
    int sel = 0;
    for (int it = 0; it < nk; ++it) {
        if (it + 1 < nk) {
            const unsigned char* Agn = Ag + (size_t)(it + 1) * 128;
            const unsigned char* Bgn = Bg + (size_t)(it + 1) * 128;
            unsigned char* AsW = As + (sel ^ 1) * ABUF + wave * 1024;
            unsigned char* BsW = Bs + (sel ^ 1) * BBUF + wave * 1024;
            #pragma unroll
            for (int q = 0; q < TI; q++) async16(Agn + (size_t)q * 32 * NN, AsW + q * 4096);
            #pragma unroll
            for (int q = 0; q < 4;  q++) async16(Bgn + (size_t)q * 32 * NN, BsW + q * 4096);
            if constexpr (TI == 4)      asm volatile("s_waitcnt vmcnt(8)" ::: "memory");
            else if constexpr (TI == 2) asm volatile("s_waitcnt vmcnt(6)" ::: "memory");
            else                        asm volatile("s_waitcnt vmcnt(0)" ::: "memory");
        } else {
            asm volatile("s_waitcnt vmcnt(0)" ::: "memory");
        }
        __builtin_amdgcn_s_barrier();
        __builtin_amdgcn_sched_barrier(0);
        const unsigned char* Ab = As + sel * ABUF;
        const unsigned char* Bb = Bs + sel * BBUF;
        #pragma unroll
        for (int kq = 0; kq < 4; kq++) {
            long a[TI], b[4];
            #pragma unroll
            for (int i = 0; i < TI; i++) a[i] = *(const long*)(Ab + (wr + i*16 + fr) * 128 + offk[kq]);
            #pragma unroll
            for (int j = 0; j < 4;  j++) b[j] = *(const long*)(Bb + (wc + j*16 + fr) * 128 + offk[kq]);
            #pragma unroll
            for (int i = 0; i < TI; i++)
                #pragma unroll
                for (int j = 0; j < 4; j++)
                    acc[i][j] = __builtin_amdgcn_mfma_f32_16x16x32_fp8_fp8(
                        a[i], b[j], acc[i][j], 0, 0, 0);
        }
        __builtin_amdgcn_s_barrier();
        sel ^= 1;
    }
}

// ---------------- prep (once per launch) ----------------

__global__ __launch_bounds__(256) void k_prep_a(const float* __restrict__ A,
                                                unsigned char* __restrict__ A8) {
    size_t i = (size_t)blockIdx.x * blockDim.x + threadIdx.x;
    size_t stride = (size_t)gridDim.x * blockDim.x;
    size_t total = (size_t)NN * NN / 4;
    for (; i < total; i += stride) {
        float4 v = ((const float4*)A)[i];
        unsigned pk = (unsigned)f2e4m3(v.x * ASCALE)
                    | ((unsigned)f2e4m3(v.y * ASCALE) << 8)
                    | ((unsigned)f2e4m3(v.z * ASCALE) << 16)
                    | ((unsigned)f2e4m3(v.w * ASCALE) << 24);
        ((unsigned*)A8)[i] = pk;
    }
}

// WzTb[col][k]: gates output-column permutation chosen so that within a wave
// (64-col span), fragment index j == gate and lane fr == h_lo:
//   col -> gate = (col>>4)&3, h = (col>>6)*16 + (col&15), oc = gate*256 + h.
//   k<256 -> rkernel[k][oc]; 256<=k<272 -> kernel[k-256][oc]; else 0.
// biasg[col] = lb[oc(col)].
// WgT[col][k] col 0..511, k 0..255: col<256 -> Wgh[k][col] else Wgc[k][col-256]
// WU[col][k]  col 0..511, k 0..511 (h-upd | c-upd)
__global__ __launch_bounds__(256) void k_prep_w(
    const float* __restrict__ Wgh, const float* __restrict__ Wgc,
    const float* __restrict__ rk,  const float* __restrict__ kern,
    const float* __restrict__ lb,
    const float* __restrict__ Whc, const float* __restrict__ Whp,
    const float* __restrict__ Wcc, const float* __restrict__ Wcp,
    unsigned short* __restrict__ WzTb, unsigned short* __restrict__ WgT,
    unsigned short* __restrict__ WU, float* __restrict__ biasg)
{
    int i = blockIdx.x * blockDim.x + threadIdx.x;
    int stride = gridDim.x * blockDim.x;
    for (int x = i; x < 1024 * KG; x += stride) {
        int col = x / KG, k = x % KG;
        int oc = (((col >> 4) & 3) << 8) + ((col >> 6) << 4) + (col & 15);
        float val = 0.f;
        if (k < 256) val = rk[k * 1024 + oc];
        else if (k < 272) val = kern[(k - 256) * 1024 + oc];
        WzTb[x] = f2bf(val);
    }
    for (int x = i; x < 512 * 256; x += stride) {
        int col = x >> 8, k = x & 255;
        float val = (col < 256) ? Wgh[k * 256 + col] : Wgc[k * 256 + (col - 256)];
        WgT[x] = f2bf(val);
    }
    for (int x = i; x < 512 * 512; x += stride) {
        int col = x >> 9, k = x & 511;
        float val;
        if (col < 256)
            val = (k < 256) ? Whc[k * 256 + col] : Whp[(k - 256) * 256 + col];
        else {
            int c2 = col - 256;
            val = (k < 256) ? Wcc[k * 256 + c2] : Wcp[(k - 256) * 256 + c2];
        }
        WU[x] = f2bf(val);
    }
    for (int x = i; x < 1024; x += stride)
        biasg[x] = lb[(((x >> 4) & 3) << 8) + ((x >> 6) << 4) + (x & 15)];
}

__global__ __launch_bounds__(256) void k_prep_s(const float* __restrict__ inputs,
                                                unsigned short* __restrict__ HCb,
                                                unsigned char* __restrict__ hwT8,
                                                float* __restrict__ Cstate)
{
    int i = blockIdx.x * blockDim.x + threadIdx.x;
    int stride = gridDim.x * blockDim.x;
    for (int x = i; x < NN * KG; x += stride) {
        int n = x / KG, col = x % KG;
        unsigned short v = 0;
        if (col >= 256 && col < 272)
            v = f2bf(inputs[(size_t)n * TD + (col - 256)]);
        HCb[x] = v;
    }
    for (int x = i; x < 512 * NN / 4; x += stride) ((unsigned*)hwT8)[x] = 0;
    for (int x = i; x < NN * HH; x += stride) Cstate[x] = 0.f;
}

// ---------------- per-step kernels ----------------

// kA: 512 blocks, 2/CU.
//  bid<256: graph states, 64x128 tiles, K=4096:
//    G = tanh(A8 @ hwT8^T * AINV2 + bg) -> LHS3 graph cols (bf16).
//    XCD-aware: xcd = bid&7 owns 8 row-tiles x all 4 col-tiles.
//  bid>=256: gates GEMM + LSTM elementwise (shuffle-free: j==gate, fr==h_lo).
// LHS3: [h_cur(0-255) | h_graph(256-511) | c_cur(512-767) | c_graph(768-1023)]
__global__ __launch_bounds__(256, 2) void k_a(
    const unsigned char* __restrict__ A8,     // [4096][4096] (x4096 scale)
    const unsigned char* __restrict__ hwT8,   // [512][4096]: HWh 0-255, HWc 256-511 (x64)
    const float* __restrict__ bgh, const float* __restrict__ bgc,
    const unsigned short* __restrict__ HCb,   // [4096][KG]
    const unsigned short* __restrict__ WzTb,  // [1024][KG]
    const float* __restrict__ biasg,
    const float* __restrict__ Cstate,
    unsigned short* __restrict__ LHS3)        // [4096][1024]
{
    __shared__ __align__(16) unsigned char smem[65536];
    const int bid = blockIdx.x;
    const int tid = threadIdx.x;
    const int lane = tid & 63;
    const int wave = tid >> 6;
    const int fr = lane & 15;
    const int rq = (lane >> 4) * 4;

    if (bid < 256) {
        // XCD remap: xcd = bid&7 -> row-tiles [xcd*8, xcd*8+8), col-tiles 0..3
        const int x  = bid & 7;
        const int q  = bid >> 3;                // 0..31
        const int row0 = (x * 8 + (q & 7)) * 64;
        const int col0 = (q >> 3) * 128;
        f32x4 acc[2][4] = {};
        gemm8_db<2>(A8, hwT8, 0, NN, row0, col0, smem, smem + 16384, acc);
        const int wr = (wave >> 1) * 32;
        const int wc = (wave & 1) * 64;
        #pragma unroll
        for (int i = 0; i < 2; i++)
            #pragma unroll
            for (int j = 0; j < 4; j++) {
                int c = col0 + wc + j * 16 + fr;          // HW col 0..511
                float bias = (c < 256) ? bgh[c] : bgc[c - 256];
                int dst = (c < 256) ? (c + 256) : (c + 512);
                int rbase = row0 + wr + i * 16 + rq;
                #pragma unroll
                for (int r = 0; r < 4; r++)
                    LHS3[(size_t)(rbase + r) * 1024 + dst] =
                        f2bf(tanhf_(acc[i][j][r] * AINV2 + bias));
            }
    } else {
        // ---- gates: z = [h|x] @ Wz + b -> LSTM elementwise (no shuffles) ----
        const int b2 = bid - 256;
        f32x4 acc[4][4] = {};
        const int row0 = (b2 >> 3) * 128;
        const int col0 = (b2 & 7) * 128;
        gemm_core_db<4>(HCb, KG, WzTb, KG, KG, row0, col0,
                        (unsigned short*)smem, (unsigned short*)(smem + 32768), acc);
        const int wr = (wave >> 1) * 64, wc = (wave & 1) * 64;
        // col = col0+wc+j*16+fr: gate==j, h = ((col0+wc)>>6)*16 + fr
        const int h = (((col0 + wc) >> 6) << 4) + fr;
        float bgv[4];
        #pragma unroll
        for (int j = 0; j < 4; j++) bgv[j] = biasg[col0 + wc + j * 16 + fr];
        #pragma unroll
        for (int i = 0; i < 4; i++) {
            const int rbase = row0 + wr + i * 16 + rq;
            #pragma unroll
            for (int r = 0; r < 4; r++) {
                const int n = rbase + r;
                float z_i = acc[i][0][r] + bgv[0];
                float z_f = acc[i][1][r] + bgv[1];
                float z_g = acc[i][2][r] + bgv[2];
                float z_o = acc[i][3][r] + bgv[3];
                float cp = Cstate[n * HH + h];
                float ccur = sigmoidf_(z_f) * cp + sigmoidf_(z_i) * tanhf_(z_g);
                float hcur = sigmoidf_(z_o) * tanhf_(ccur);
                LHS3[(size_t)n * 1024 + h] = f2bf(hcur);
                LHS3[(size_t)n * 1024 + 512 + h] = f2bf(ccur);
            }
        }
    }
}

// k_uf (fused): 512 blocks, per block: 16 rows x one U-half (256 cols).
//  stage1: U = sigmoid(LHS3[:,half*512:+512] @ WU[:,half*256:+256] + b), K=512.
//    DIRECT-LOAD GEMM: A/B fragments straight from global (L2-resident WU,
//    16 LHS3 rows) -- no LDS staging, no barriers. Swizzle cancels:
//    a = LHS3[row0+fr][half*512 + it*64 + kh*32 + fq*8 .. +8]  (16B load)
//    b[j] = WU[half*256+wc+j*16+fr][it*64 + kh*32 + fq*8 .. +8]
//  epilogue: U -> LDS (swizzled bf16), HCb/Cstate, out_pred (half 0)
//  stage2: HW = U @ Wg^T (K=256): A from Us (LDS), B direct from WgT.
//  LDS total 8.7KB -> occupancy capped by VGPR only.
__global__ __launch_bounds__(256, 4) void k_uf(
    const unsigned short* __restrict__ LHS3,  // [4096][1024]
    const unsigned short* __restrict__ WU,    // [512][512]
    const unsigned short* __restrict__ WgT,   // [512][256]
    const float* __restrict__ b_h, const float* __restrict__ b_c,
    const float* __restrict__ W_out, const float* __restrict__ b_out,
    float* __restrict__ Cstate,
    unsigned short* __restrict__ HCb,
    unsigned char* __restrict__ hwT8,         // [512][4096]
    float* __restrict__ d_out,
    const float* __restrict__ inputs, int t)
{
    // LDS map: Us @0 (16x256 shorts = 8KB), outred @8192 (512B)
    __shared__ __align__(16) unsigned char smem[8704];
    unsigned short* Us = (unsigned short*)smem;
    float* outred = (float*)(smem + 8192);

    const int bid  = blockIdx.x;
    const int tid  = threadIdx.x;
    const int lane = tid & 63;
    const int wave = tid >> 6;
    const int fr   = lane & 15;
    const int fq   = lane >> 4;
    const int rq   = fq * 4;

    const int half = bid & 1;
    const int row0 = (bid >> 1) * 16;
    const int wc   = wave * 64;
    const int off0 = ((fq ^ (fr & 7)) * 8);

    // ---- stage 1: direct-load GEMM, K=512, no LDS, no barriers ----
    const unsigned short* Arow = LHS3 + (size_t)(row0 + fr) * 1024 + half*512 + fq*8;
    const unsigned short* Brow[4];
    #pragma unroll
    for (int j = 0; j < 4; j++)
        Brow[j] = WU + (size_t)(half*256 + wc + j*16 + fr) * 512 + fq*8;

    f32x4 acc[4] = {};
    #pragma unroll
    for (int it = 0; it < 8; ++it) {
        #pragma unroll
        for (int kh2 = 0; kh2 < 2; kh2++) {
            const int ko = it*64 + kh2*32;
            short8 a = *(const short8*)(Arow + ko);
            short8 b[4];
            #pragma unroll
            for (int j = 0; j < 4; j++)
                b[j] = *(const short8*)(Brow[j] + ko);
            #pragma unroll
            for (int j = 0; j < 4; j++)
                acc[j] = __builtin_amdgcn_mfma_f32_16x16x32_bf16(
                    a, b[j], acc[j], 0, 0, 0);
        }
    }

    // ---- stage-1 epilogue: sigmoid, write Us(swizzled)/HCb/Cstate, out partials
    const float* bias = half ? b_c : b_h;
    float pr0[4], pr1[4];
    #pragma unroll
    for (int m = 0; m < 4; m++) { pr0[m] = 0.f; pr1[m] = 0.f; }
    #pragma unroll
    for (int j = 0; j < 4; j++) {
        const int cl = wc + j*16 + fr;                // 0..255 within half
        const float bv = bias[cl];
        const int blk = j*2 + (fr >> 3);
        float w0 = 0.f, w1 = 0.f;
        if (half == 0) { w0 = W_out[cl*2 + 0]; w1 = W_out[cl*2 + 1]; }
        #pragma unroll
        for (int r = 0; r < 4; r++) {
            const int rl = rq + r;                    // 0..15
            const int n = row0 + rl;
            float v = sigmoidf_(acc[j][r] + bv);
            unsigned short vb = f2bf(v);
            Us[rl*256 + wave*64 + ((blk ^ (rl & 7)) * 8) + (fr & 7)] = vb;
            if (half == 0) {
                HCb[(size_t)n * KG + cl] = vb;
                pr0[r] += v * w0;
                pr1[r] += v * w1;
            } else {
                Cstate[(size_t)n * HH + cl] = v;
            }
        }
    }
    if (half == 0) {
        #pragma unroll
        for (int m = 0; m < 4; m++) {
            #pragma unroll
            for (int s = 1; s < 16; s <<= 1) {
                pr0[m] += __shfl_xor(pr0[m], s, 64);
                pr1[m] += __shfl_xor(pr1[m], s, 64);
            }
        }
        if (fr == 0) {
            #pragma unroll
            for (int r = 0; r < 4; r++) {
                int rl = rq + r;
                outred[(wave*16 + rl)*2 + 0] = pr0[r];
                outred[(wave*16 + rl)*2 + 1] = pr1[r];
            }
        }
    }
    __syncthreads();   // Us + outred visible
    if (half == 0 && tid < 32) {
        int rl = tid >> 1, p = tid & 1;
        float s = b_out[p];
        #pragma unroll
        for (int w = 0; w < 4; w++) s += outred[(w*16 + rl)*2 + p];
        d_out[(size_t)(row0 + rl) * TP + t * PP + p] = s;
    }

    // ---- stage 2: HW = U @ Wg^T, K=256: A from Us (LDS), B direct ----
    f32x4 acc2[4] = {};
    const unsigned short* B2row[4];
    #pragma unroll
    for (int j = 0; j < 4; j++)
        B2row[j] = WgT + (size_t)(half*256 + wc + j*16 + fr) * 256 + fq*8;
    #pragma unroll
    for (int kc2 = 0; kc2 < 4; ++kc2) {
        #pragma unroll
        for (int kh2 = 0; kh2 < 2; kh2++) {
            const int off = off0 ^ (kh2 * 32);
            const int ko = kc2*64 + kh2*32;
            short8 a = *(const short8*)(Us + fr * 256 + kc2*64 + off);
            short8 b[4];
            #pragma unroll
            for (int j = 0; j < 4; j++)
                b[j] = *(const short8*)(B2row[j] + ko);
            #pragma unroll
            for (int j = 0; j < 4; j++)
                acc2[j] = __builtin_amdgcn_mfma_f32_16x16x32_bf16(
                    a, b[j], acc2[j], 0, 0, 0);
        }
    }
    // hwT8 fp8 store, wave-transposed to 16B/lane (4x fewer transactions).
    unsigned pk[4];
    #pragma unroll
    for (int j = 0; j < 4; j++)
        pk[j] = (unsigned)f2e4m3(acc2[j][0] * HWSCALE)
              | ((unsigned)f2e4m3(acc2[j][1] * HWSCALE) << 8)
              | ((unsigned)f2e4m3(acc2[j][2] * HWSCALE) << 16)
              | ((unsigned)f2e4m3(acc2[j][3] * HWSCALE) << 24);
    unsigned o0 = 0, o1 = 0, o2 = 0, o3 = 0;
    #pragma unroll
    for (int d = 0; d < 4; d++) {
        unsigned g0 = __shfl(pk[d],  0 + fr, 64);
        unsigned g1 = __shfl(pk[d], 16 + fr, 64);
        unsigned g2 = __shfl(pk[d], 32 + fr, 64);
        unsigned g3 = __shfl(pk[d], 48 + fr, 64);
        if (fq == d) { o0 = g0; o1 = g1; o2 = g2; o3 = g3; }
    }
    {
        int cg = half*256 + wc + fq*16 + fr;          // lane-unique col
        uint4 o; o.x = o0; o.y = o1; o.z = o2; o.w = o3;   // n = row0..row0+15
        *(uint4*)(hwT8 + (size_t)cg * NN + row0) = o;
    }

    // x_{t+1} prefetch into HCb (half==0 blocks: 256 x 256 threads = 65536)
    if (half == 0 && t + 1 < TT) {
        int gid = (bid >> 1) * 256 + tid;
        int n = gid >> 4, d = gid & 15;
        HCb[(size_t)n * KG + 256 + d] = f2bf(inputs[(size_t)n * TD + (t + 1) * DD + d]);
    }
}

extern "C" void kernel_launch(void* const* d_in, const int* in_sizes, int n_in,
                              void* d_out_v, int out_size, void* d_ws, size_t ws_size,
                              hipStream_t stream)
{
    const float* inputs = (const float*)d_in[0];
    const float* A      = (const float*)d_in[1];
    const float* kern   = (const float*)d_in[2];
    const float* rk     = (const float*)d_in[3];
    const float* lb     = (const float*)d_in[4];
    const float* Wgh    = (const float*)d_in[5];
    const float* bgh    = (const float*)d_in[6];
    const float* Wgc    = (const float*)d_in[7];
    const float* bgc    = (const float*)d_in[8];
    const float* Whc    = (const float*)d_in[9];
    const float* Whp    = (const float*)d_in[10];
    const float* bh     = (const float*)d_in[11];
    const float* Wcc    = (const float*)d_in[12];
    const float* Wcp    = (const float*)d_in[13];
    const float* bc     = (const float*)d_in[14];
    const float* Wout   = (const float*)d_in[15];
    const float* bout   = (const float*)d_in[16];
    float* d_out = (float*)d_out_v;

    char* ws = (char*)d_ws;
    size_t off = 0;
    auto alloc = [&](size_t bytes) {
        char* p = ws + off;
        off += (bytes + 255) & ~(size_t)255;
        return p;
    };
    unsigned char*  A8    = (unsigned char*) alloc((size_t)NN * NN);           // 16 MB
    unsigned char*  hwT8  = (unsigned char*) alloc((size_t)512 * NN);          // 2 MB
    unsigned short* HCb   = (unsigned short*)alloc((size_t)NN * KG * 2);       // 2.5 MB
    unsigned short* WzTb  = (unsigned short*)alloc((size_t)1024 * KG * 2);
    unsigned short* WgT   = (unsigned short*)alloc((size_t)512 * 256 * 2);
    unsigned short* WU    = (unsigned short*)alloc((size_t)512 * 512 * 2);
    float*          biasg = (float*)         alloc(1024 * 4);
    unsigned short* LHS3  = (unsigned short*)alloc((size_t)NN * 1024 * 2);     // 8 MB
    float*          Cst   = (float*)         alloc((size_t)NN * HH * 4);       // 4 MB
    (void)in_sizes; (void)n_in; (void)out_size; (void)ws_size;

    k_prep_a<<<2048, 256, 0, stream>>>(A, A8);
    k_prep_w<<<256, 256, 0, stream>>>(Wgh, Wgc, rk, kern, lb,
                                      Whc, Whp, Wcc, Wcp, WzTb, WgT, WU, biasg);
    k_prep_s<<<512, 256, 0, stream>>>(inputs, HCb, hwT8, Cst);

    for (int t = 0; t < TT; t++) {
        k_a<<<512, 256, 0, stream>>>(A8, hwT8, bgh, bgc,
                                     HCb, WzTb, biasg, Cst, LHS3);
        k_uf<<<512, 256, 0, stream>>>(LHS3, WU, WgT, bh, bc, Wout, bout,
                                      Cst, HCb, hwT8, d_out, inputs, t);
    }
}

// Round 10
// 14966.759 us; speedup vs baseline: 1.4537x; 1.4537x over previous
//
#include <hip/hip_runtime.h>

using short8 = __attribute__((ext_vector_type(8))) short;
using f32x4  = __attribute__((ext_vector_type(4))) float;

#define NN 4096
#define TT 365
#define DD 16
#define HH 256
#define PP 2
#define TD (TT*DD)      // 5840
#define TP (TT*PP)      // 730
#define KG 320          // gates K: [h(256) | x(16) | pad(48)]
#define ASCALE 4096.0f
#define HWSCALE 64.0f
#define AINV2 (1.0f/(4096.0f*64.0f))   // A8 scale * hwT8 scale

__device__ __forceinline__ unsigned short f2bf(float f) {
    union { float f; unsigned u; } v; v.f = f;
    unsigned r = v.u + 0x7FFFu + ((v.u >> 16) & 1u);   // RNE
    return (unsigned short)(r >> 16);
}
// float -> OCP e4m3fn, RNE, saturating at 448
__device__ __forceinline__ unsigned char f2e4m3(float f) {
    union { float f; unsigned u; } v; v.f = f;
    unsigned s = (v.u >> 24) & 0x80u;
    unsigned au = v.u & 0x7fffffffu;
    if (au >= 0x43E00000u) return (unsigned char)(s | 0x7E);   // >=448 -> 448
    if (au < 0x3C800000u) {                                    // <2^-6: subnormal
        int m = __float2int_rn(__uint_as_float(au) * 512.0f);  // 0..8
        return (unsigned char)(s | (unsigned)m);
    }
    unsigned r = au + 0x7FFFFu + ((au >> 20) & 1u);            // RNE to 3 mantissa bits
    return (unsigned char)(s | ((r >> 20) - 0x3C0u));
}
__device__ __forceinline__ float sigmoidf_(float x) {
    return 1.0f / (1.0f + __expf(-x));
}
__device__ __forceinline__ float tanhf_(float x) {
    float t = __expf(2.0f * x);
    return (t - 1.0f) / (t + 1.0f);
}
__device__ __forceinline__ void async16(const void* g, void* l) {
    __builtin_amdgcn_global_load_lds(
        (const __attribute__((address_space(1))) void*)g,
        (__attribute__((address_space(3))) void*)l, 16, 0, 0);
}

// ---------------------------------------------------------------------------
// bf16 core, double-buffered with COUNTED vmcnt: 256 thr = 4 waves 2x2.
// BN=128, BK=64, BM=32*TI. C = Amat(row,lda) @ Bt^T (Bt[col][k],ldb).
// ---------------------------------------------------------------------------
template<int TI>
__device__ __forceinline__ void gemm_core_db(
    const unsigned short* __restrict__ Amat, int lda,
    const unsigned short* __restrict__ Bt,  int ldb,
    int k_len, int row0, int col0,
    unsigned short* As, unsigned short* Bs,
    f32x4 (&acc)[TI][4])
{
    const int tid  = threadIdx.x;
    const int lane = tid & 63;
    const int wave = tid >> 6;
    const int srow = lane >> 3;
    const int sblk = lane & 7;
    const int ABUF = TI * 32 * 64;     // shorts per A buffer
    const int BBUF = 128 * 64;         // shorts per B buffer

    const unsigned short* Ag = Amat + (size_t)(row0 + wave*8 + srow) * lda
                                    + ((sblk ^ srow) * 8);
    const unsigned short* Bg = Bt   + (size_t)(col0 + wave*8 + srow) * ldb
                                    + ((sblk ^ srow) * 8);

    const int fr = lane & 15;
    const int fq = lane >> 4;
    const int wr = (wave >> 1) * (TI * 16);
    const int wc = (wave & 1) * 64;
    const int off0 = ((fq ^ (fr & 7)) * 8);

    {   // prologue: tile 0 -> buffer 0
        unsigned short* AsW = As + wave * 512;
        unsigned short* BsW = Bs + wave * 512;
        #pragma unroll
        for (int q = 0; q < TI; q++) async16(Ag + (size_t)q * 32 * lda, AsW + q * 2048);
        #pragma unroll
        for (int q = 0; q < 4;  q++) async16(Bg + (size_t)q * 32 * ldb, BsW + q * 2048);
    }

    const int nk = k_len >> 6;
    int sel = 0;
    for (int it = 0; it < nk; ++it) {
        if (it + 1 < nk) {
            const unsigned short* Agn = Ag + (it + 1) * 64;
            const unsigned short* Bgn = Bg + (it + 1) * 64;
            unsigned short* AsW = As + (sel ^ 1) * ABUF + wave * 512;
            unsigned short* BsW = Bs + (sel ^ 1) * BBUF + wave * 512;
            #pragma unroll
            for (int q = 0; q < TI; q++) async16(Agn + (size_t)q * 32 * lda, AsW + q * 2048);
            #pragma unroll
            for (int q = 0; q < 4;  q++) async16(Bgn + (size_t)q * 32 * ldb, BsW + q * 2048);
            if constexpr (TI == 4)      asm volatile("s_waitcnt vmcnt(8)" ::: "memory");
            else if constexpr (TI == 2) asm volatile("s_waitcnt vmcnt(6)" ::: "memory");
            else                        asm volatile("s_waitcnt vmcnt(0)" ::: "memory");
        } else {
            asm volatile("s_waitcnt vmcnt(0)" ::: "memory");
        }
        __builtin_amdgcn_s_barrier();          // all waves: tile(it) landed
        __builtin_amdgcn_sched_barrier(0);
        const unsigned short* Ab = As + sel * ABUF;
        const unsigned short* Bb = Bs + sel * BBUF;
        #pragma unroll
        for (int kh = 0; kh < 2; kh++) {
            const int off = off0 ^ (kh * 32);
            short8 a[TI], b[4];
            #pragma unroll
            for (int i = 0; i < TI; i++)
                a[i] = *(const short8*)(Ab + (wr + i*16 + fr) * 64 + off);
            #pragma unroll
            for (int j = 0; j < 4;  j++)
                b[j] = *(const short8*)(Bb + (wc + j*16 + fr) * 64 + off);
            #pragma unroll
            for (int i = 0; i < TI; i++)
                #pragma unroll
                for (int j = 0; j < 4; j++)
                    acc[i][j] = __builtin_amdgcn_mfma_f32_16x16x32_bf16(
                        a[i], b[j], acc[i][j], 0, 0, 0);
        }
        __builtin_amdgcn_s_barrier();          // reads of buf[sel] done
        sel ^= 1;
    }
}

// ---------------------------------------------------------------------------
// fp8 core, double-buffered with COUNTED vmcnt, BM=32*TI x BN=16*BJ*2 tile:
// C = A8 @ B8^T, both row-major [*][NN] bytes, BK=128.
// Wave grid 2x2: wave owns TI*16 rows x BJ*16 cols.
// ---------------------------------------------------------------------------
template<int TI, int BJ>
__device__ __forceinline__ void gemm8_db(
    const unsigned char* __restrict__ Amat,
    const unsigned char* __restrict__ Bmat,
    int kb, int klen, int row0, int col0,
    unsigned char* As, unsigned char* Bs,
    f32x4 (&acc)[TI][BJ])
{
    const int tid  = threadIdx.x;
    const int lane = tid & 63;
    const int wave = tid >> 6;
    const int srow = lane >> 3;
    const int sblk = lane & 7;
    const int ABUF = TI * 32 * 128;
    const int BBUF = BJ * 32 * 128;

    const unsigned char* Ag = Amat + (size_t)(row0 + wave*8 + srow) * NN
                                   + ((sblk ^ srow) * 16) + kb;
    const unsigned char* Bg = Bmat + (size_t)(col0 + wave*8 + srow) * NN
                                   + ((sblk ^ srow) * 16) + kb;

    const int fr = lane & 15;
    const int fq = lane >> 4;
    const int wr = (wave >> 1) * (TI * 16);
    const int wc = (wave & 1) * (BJ * 16);
    int offk[4];
    #pragma unroll
    for (int kq = 0; kq < 4; kq++)
        offk[kq] = (((kq*2 + (fq >> 1)) ^ (fr & 7)) << 4) + ((fq & 1) << 3);

    {   // prologue
        unsigned char* AsW = As + wave * 1024;
        unsigned char* BsW = Bs + wave * 1024;
        #pragma unroll
        for (int q = 0; q < TI; q++) async16(Ag + (size_t)q * 32 * NN, AsW + q * 4096);
        #pragma unroll
        for (int q = 0; q < BJ; q++) async16(Bg + (size_t)q * 32 * NN, BsW + q * 4096);
    }

    const int nk = klen >> 7;
    int sel = 0;
    for (int it = 0; it < nk; ++it) {
        if (it + 1 < nk) {
            const unsigned char* Agn = Ag + (size_t)(it + 1) * 128;
            const unsigned char* Bgn = Bg + (size_t)(it + 1) * 128;
            unsigned char* AsW = As + (sel ^ 1) * ABUF + wave * 1024;
            unsigned char* BsW = Bs + (sel ^ 1) * BBUF + wave * 1024;
            #pragma unroll
            for (int q = 0; q < TI; q++) async16(Agn + (size_t)q * 32 * NN, AsW + q * 4096);
            #pragma unroll
            for (int q = 0; q < BJ; q++) async16(Bgn + (size_t)q * 32 * NN, BsW + q * 4096);
            if constexpr (TI + BJ == 8)      asm volatile("s_waitcnt vmcnt(8)" ::: "memory");
            else if constexpr (TI + BJ == 6) asm volatile("s_waitcnt vmcnt(6)" ::: "memory");
            else if constexpr (TI + BJ == 4) asm volatile("s_waitcnt vmcnt(4)" ::: "memory");
            else                             asm volatile("s_waitcnt vmcnt(0)" ::: "memory");
        } else {
            asm volatile("s_waitcnt vmcnt(0)" ::: "memory");
        }
        __builtin_amdgcn_s_barrier();
        __builtin_amdgcn_sched_barrier(0);
        const unsigned char* Ab = As + sel * ABUF;
        const unsigned char* Bb = Bs + sel * BBUF;
        #pragma unroll
        for (int kq = 0; kq < 4; kq++) {
            long a[TI], b[BJ];
            #pragma unroll
            for (int i = 0; i < TI; i++) a[i] = *(const long*)(Ab + (wr + i*16 + fr) * 128 + offk[kq]);
            #pragma unroll
            for (int j = 0; j < BJ; j++) b[j] = *(const long*)(Bb + (wc + j*16 + fr) * 128 + offk[kq]);
            #pragma unroll
            for (int i = 0; i < TI; i++)
                #pragma unroll
                for (int j = 0; j < BJ; j++)
                    acc[i][j] = __builtin_amdgcn_mfma_f32_16x16x32_fp8_fp8(
                        a[i], b[j], acc[i][j], 0, 0, 0);
        }
        __builtin_amdgcn_s_barrier();
        sel ^= 1;
    }
}

// ---------------- prep (once per launch) ----------------

__global__ __launch_bounds__(256) void k_prep_a(const float* __restrict__ A,
                                                unsigned char* __restrict__ A8) {
    size_t i = (size_t)blockIdx.x * blockDim.x + threadIdx.x;
    size_t stride = (size_t)gridDim.x * blockDim.x;
    size_t total = (size_t)NN * NN / 4;
    for (; i < total; i += stride) {
        float4 v = ((const float4*)A)[i];
        unsigned pk = (unsigned)f2e4m3(v.x * ASCALE)
                    | ((unsigned)f2e4m3(v.y * ASCALE) << 8)
                    | ((unsigned)f2e4m3(v.z * ASCALE) << 16)
                    | ((unsigned)f2e4m3(v.w * ASCALE) << 24);
        ((unsigned*)A8)[i] = pk;
    }
}

// WzTb[col][k]: gates output-column permutation chosen so that within a wave
// (64-col span), fragment index j == gate and lane fr == h_lo:
//   col -> gate = (col>>4)&3, h = (col>>6)*16 + (col&15), oc = gate*256 + h.
//   k<256 -> rkernel[k][oc]; 256<=k<272 -> kernel[k-256][oc]; else 0.
// biasg[col] = lb[oc(col)].
// WgT[col][k] col 0..511, k 0..255: col<256 -> Wgh[k][col] else Wgc[k][col-256]
// WU[col][k]  col 0..511, k 0..511 (h-upd | c-upd)
__global__ __launch_bounds__(256) void k_prep_w(
    const float* __restrict__ Wgh, const float* __restrict__ Wgc,
    const float* __restrict__ rk,  const float* __restrict__ kern,
    const float* __restrict__ lb,
    const float* __restrict__ Whc, const float* __restrict__ Whp,
    const float* __restrict__ Wcc, const float* __restrict__ Wcp,
    unsigned short* __restrict__ WzTb, unsigned short* __restrict__ WgT,
    unsigned short* __restrict__ WU, float* __restrict__ biasg)
{
    int i = blockIdx.x * blockDim.x + threadIdx.x;
    int stride = gridDim.x * blockDim.x;
    for (int x = i; x < 1024 * KG; x += stride) {
        int col = x / KG, k = x % KG;
        int oc = (((col >> 4) & 3) << 8) + ((col >> 6) << 4) + (col & 15);
        float val = 0.f;
        if (k < 256) val = rk[k * 1024 + oc];
        else if (k < 272) val = kern[(k - 256) * 1024 + oc];
        WzTb[x] = f2bf(val);
    }
    for (int x = i; x < 512 * 256; x += stride) {
        int col = x >> 8, k = x & 255;
        float val = (col < 256) ? Wgh[k * 256 + col] : Wgc[k * 256 + (col - 256)];
        WgT[x] = f2bf(val);
    }
    for (int x = i; x < 512 * 512; x += stride) {
        int col = x >> 9, k = x & 511;
        float val;
        if (col < 256)
            val = (k < 256) ? Whc[k * 256 + col] : Whp[(k - 256) * 256 + col];
        else {
            int c2 = col - 256;
            val = (k < 256) ? Wcc[k * 256 + c2] : Wcp[(k - 256) * 256 + c2];
        }
        WU[x] = f2bf(val);
    }
    for (int x = i; x < 1024; x += stride)
        biasg[x] = lb[(((x >> 4) & 3) << 8) + ((x >> 6) << 4) + (x & 15)];
}

__global__ __launch_bounds__(256) void k_prep_s(const float* __restrict__ inputs,
                                                unsigned short* __restrict__ HCb,
                                                unsigned char* __restrict__ hwT8,
                                                float* __restrict__ Cstate)
{
    int i = blockIdx.x * blockDim.x + threadIdx.x;
    int stride = gridDim.x * blockDim.x;
    for (int x = i; x < NN * KG; x += stride) {
        int n = x / KG, col = x % KG;
        unsigned short v = 0;
        if (col >= 256 && col < 272)
            v = f2bf(inputs[(size_t)n * TD + (col - 256)]);
        HCb[x] = v;
    }
    for (int x = i; x < 512 * NN / 4; x += stride) ((unsigned*)hwT8)[x] = 0;
    for (int x = i; x < NN * HH; x += stride) Cstate[x] = 0.f;
}

// ---------------- per-step kernels ----------------

// kA: 1024 blocks, 3/CU (48KB smem each) -> fp8 bulk keeps 2-3 blocks/CU.
//  bid<512: graph states, 64x64 fp8 tiles, K=4096:
//    G = tanh(A8 @ hwT8^T * AINV2 + bg) -> LHS3 graph cols (bf16).
//    XCD-aware: xcd = bid&7 owns 8 row-tiles x all 8 col-tiles.
//  bid>=512: gates GEMM 64x128 (TI=2) + LSTM elementwise (shuffle-free).
// LHS3: [h_cur(0-255) | h_graph(256-511) | c_cur(512-767) | c_graph(768-1023)]
__global__ __launch_bounds__(256, 3) void k_a(
    const unsigned char* __restrict__ A8,     // [4096][4096] (x4096 scale)
    const unsigned char* __restrict__ hwT8,   // [512][4096]: HWh 0-255, HWc 256-511 (x64)
    const float* __restrict__ bgh, const float* __restrict__ bgc,
    const unsigned short* __restrict__ HCb,   // [4096][KG]
    const unsigned short* __restrict__ WzTb,  // [1024][KG]
    const float* __restrict__ biasg,
    const float* __restrict__ Cstate,
    unsigned short* __restrict__ LHS3)        // [4096][1024]
{
    __shared__ __align__(16) unsigned char smem[49152];
    const int bid = blockIdx.x;
    const int tid = threadIdx.x;
    const int lane = tid & 63;
    const int wave = tid >> 6;
    const int fr = lane & 15;
    const int rq = (lane >> 4) * 4;

    if (bid < 512) {
        // XCD remap: xcd = bid&7 -> row-tiles [xcd*8, xcd*8+8), col-tiles 0..7
        const int x  = bid & 7;
        const int q  = bid >> 3;                // 0..63
        const int row0 = (x * 8 + (q & 7)) * 64;
        const int col0 = (q >> 3) * 64;
        f32x4 acc[2][2] = {};
        gemm8_db<2, 2>(A8, hwT8, 0, NN, row0, col0, smem, smem + 16384, acc);
        const int wr = (wave >> 1) * 32;
        const int wc = (wave & 1) * 32;
        #pragma unroll
        for (int i = 0; i < 2; i++)
            #pragma unroll
            for (int j = 0; j < 2; j++) {
                int c = col0 + wc + j * 16 + fr;          // HW col 0..511
                float bias = (c < 256) ? bgh[c] : bgc[c - 256];
                int dst = (c < 256) ? (c + 256) : (c + 512);
                int rbase = row0 + wr + i * 16 + rq;
                #pragma unroll
                for (int r = 0; r < 4; r++)
                    LHS3[(size_t)(rbase + r) * 1024 + dst] =
                        f2bf(tanhf_(acc[i][j][r] * AINV2 + bias));
            }
    } else {
        // ---- gates: z = [h|x] @ Wz + b -> LSTM elementwise (no shuffles) ----
        const int b2 = bid - 512;               // 0..511
        f32x4 acc[2][4] = {};
        const int row0 = (b2 >> 3) * 64;
        const int col0 = (b2 & 7) * 128;
        gemm_core_db<2>(HCb, KG, WzTb, KG, KG, row0, col0,
                        (unsigned short*)smem, (unsigned short*)(smem + 16384), acc);
        const int wr = (wave >> 1) * 32, wc = (wave & 1) * 64;
        // col = col0+wc+j*16+fr: gate==j, h = ((col0+wc)>>6)*16 + fr
        const int h = (((col0 + wc) >> 6) << 4) + fr;
        float bgv[4];
        #pragma unroll
        for (int j = 0; j < 4; j++) bgv[j] = biasg[col0 + wc + j * 16 + fr];
        #pragma unroll
        for (int i = 0; i < 2; i++) {
            const int rbase = row0 + wr + i * 16 + rq;
            #pragma unroll
            for (int r = 0; r < 4; r++) {
                const int n = rbase + r;
                float z_i = acc[i][0][r] + bgv[0];
                float z_f = acc[i][1][r] + bgv[1];
                float z_g = acc[i][2][r] + bgv[2];
                float z_o = acc[i][3][r] + bgv[3];
                float cp = Cstate[n * HH + h];
                float ccur = sigmoidf_(z_f) * cp + sigmoidf_(z_i) * tanhf_(z_g);
                float hcur = sigmoidf_(z_o) * tanhf_(ccur);
                LHS3[(size_t)n * 1024 + h] = f2bf(hcur);
                LHS3[(size_t)n * 1024 + 512 + h] = f2bf(ccur);
            }
        }
    }
}

// k_uf (fused): 512 blocks (2/CU), per block: 16 rows x one U-half (256 cols).
//  stage1: U = sigmoid(LHS3[:,half*512:+512] @ WU[:,half*256:+256] + b), K=512,
//          counted-vmcnt double-buffered LDS staging (R8-proven).
//  epilogue: U -> LDS (swizzled bf16), HCb/Cstate, out_pred (half 0)
//  stage2: HW = U @ Wg^T (K=256, block-local), double-buffered B,
//          -> x64 -> fp8 coalesced hwT8
__global__ __launch_bounds__(256, 2) void k_uf(
    const unsigned short* __restrict__ LHS3,  // [4096][1024]
    const unsigned short* __restrict__ WU,    // [512][512]
    const unsigned short* __restrict__ WgT,   // [512][256]
    const float* __restrict__ b_h, const float* __restrict__ b_c,
    const float* __restrict__ W_out, const float* __restrict__ b_out,
    float* __restrict__ Cstate,
    unsigned short* __restrict__ HCb,
    unsigned char* __restrict__ hwT8,         // [512][4096]
    float* __restrict__ d_out,
    const float* __restrict__ inputs, int t)
{
    // LDS map:
    //  stage1: As @0 (2 x 16x64 shorts = 4KB), Bs @8192 (2 x 256x64 = 64KB)
    //  stage2 alias: Us @0 (16x256 shorts = 8KB), B2s @8192 (2 x 256x64 = 64KB)
    //  outred @73728 (512B)
    __shared__ __align__(16) unsigned char smem[74752];
    unsigned short* As  = (unsigned short*)smem;
    unsigned short* Bs  = (unsigned short*)(smem + 8192);
    unsigned short* Us  = (unsigned short*)smem;
    unsigned short* B2s = (unsigned short*)(smem + 8192);
    float* outred = (float*)(smem + 73728);

    const int bid  = blockIdx.x;
    const int tid  = threadIdx.x;
    const int lane = tid & 63;
    const int wave = tid >> 6;
    const int fr   = lane & 15;
    const int fq   = lane >> 4;
    const int rq   = fq * 4;
    const int srow = lane >> 3;
    const int sblk = lane & 7;

    const int half = bid & 1;
    const int row0 = (bid >> 1) * 16;
    const int wc   = wave * 64;
    const int off0 = ((fq ^ (fr & 7)) * 8);
    const int ABUF = 1024, BBUF = 16384;      // shorts per buffer

    const unsigned short* Ag = LHS3 + half*512
        + (size_t)(row0 + wave*8 + srow) * 1024 + ((sblk ^ srow) * 8);
    const unsigned short* Bg = WU
        + (size_t)(half*256 + wave*64 + srow) * 512 + ((sblk ^ srow) * 8);

    // prologue: stage chunk 0
    if (wave < 2) async16(Ag, As + wave*512);
    #pragma unroll
    for (int q = 0; q < 8; q++)
        async16(Bg + (size_t)q*8*512, Bs + wave*4096 + q*512);

    f32x4 acc[4] = {};
    int sel = 0;
    for (int it = 0; it < 8; ++it) {
        const int nit = it + 1;
        if (nit < 8) {
            if (wave < 2) async16(Ag + nit*64, As + (sel^1)*ABUF + wave*512);
            #pragma unroll
            for (int q = 0; q < 8; q++)
                async16(Bg + nit*64 + (size_t)q*8*512,
                        Bs + (sel^1)*BBUF + wave*4096 + q*512);
            if (wave < 2) asm volatile("s_waitcnt vmcnt(9)" ::: "memory");
            else          asm volatile("s_waitcnt vmcnt(8)" ::: "memory");
        } else {
            asm volatile("s_waitcnt vmcnt(0)" ::: "memory");
        }
        __builtin_amdgcn_s_barrier();
        __builtin_amdgcn_sched_barrier(0);
        const unsigned short* Ab = As + sel*ABUF;
        const unsigned short* Bb = Bs + sel*BBUF;
        #pragma unroll
        for (int kh2 = 0; kh2 < 2; kh2++) {
            const int off = off0 ^ (kh2 * 32);
            short8 a = *(const short8*)(Ab + fr * 64 + off);
            short8 b[4];
            #pragma unroll
            for (int j = 0; j < 4; j++)
                b[j] = *(const short8*)(Bb + (wc + j*16 + fr) * 64 + off);
            #pragma unroll
            for (int j = 0; j < 4; j++)
                acc[j] = __builtin_amdgcn_mfma_f32_16x16x32_bf16(
                    a, b[j], acc[j], 0, 0, 0);
        }
        __builtin_amdgcn_s_barrier();
        sel ^= 1;
    }

    // ---- stage-1 epilogue: sigmoid, write Us(swizzled)/HCb/Cstate, out partials
    const float* bias = half ? b_c : b_h;
    float pr0[4], pr1[4];
    #pragma unroll
    for (int m = 0; m < 4; m++) { pr0[m] = 0.f; pr1[m] = 0.f; }
    #pragma unroll
    for (int j = 0; j < 4; j++) {
        const int cl = wc + j*16 + fr;                // 0..255 within half
        const float bv = bias[cl];
        const int blk = j*2 + (fr >> 3);
        float w0 = 0.f, w1 = 0.f;
        if (half == 0) { w0 = W_out[cl*2 + 0]; w1 = W_out[cl*2 + 1]; }
        #pragma unroll
        for (int r = 0; r < 4; r++) {
            const int rl = rq + r;                    // 0..15
            const int n = row0 + rl;
            float v = sigmoidf_(acc[j][r] + bv);
            unsigned short vb = f2bf(v);
            Us[rl*256 + wave*64 + ((blk ^ (rl & 7)) * 8) + (fr & 7)] = vb;
            if (half == 0) {
                HCb[(size_t)n * KG + cl] = vb;
                pr0[r] += v * w0;
                pr1[r] += v * w1;
            } else {
                Cstate[(size_t)n * HH + cl] = v;
            }
        }
    }
    if (half == 0) {
        #pragma unroll
        for (int m = 0; m < 4; m++) {
            #pragma unroll
            for (int s = 1; s < 16; s <<= 1) {
                pr0[m] += __shfl_xor(pr0[m], s, 64);
                pr1[m] += __shfl_xor(pr1[m], s, 64);
            }
        }
        if (fr == 0) {
            #pragma unroll
            for (int r = 0; r < 4; r++) {
                int rl = rq + r;
                outred[(wave*16 + rl)*2 + 0] = pr0[r];
                outred[(wave*16 + rl)*2 + 1] = pr1[r];
            }
        }
    }
    __syncthreads();   // Us + outred visible (full drain, outside hot loop)
    if (half == 0 && tid < 32) {
        int rl = tid >> 1, p = tid & 1;
        float s = b_out[p];
        #pragma unroll
        for (int w = 0; w < 4; w++) s += outred[(w*16 + rl)*2 + p];
        d_out[(size_t)(row0 + rl) * TP + t * PP + p] = s;
    }

    // ---- stage 2: HW = U @ Wg^T, K=256 (block-local), 4 chunks,
    //      double-buffered B2s with counted vmcnt
    f32x4 acc2[4] = {};
    const unsigned short* Bg2 = WgT
        + (size_t)(half*256 + wave*64 + srow) * 256 + ((sblk ^ srow) * 8);
    // prologue: chunk 0 -> B2s buf0
    #pragma unroll
    for (int q = 0; q < 8; q++)
        async16(Bg2 + (size_t)q*8*256, B2s + wave*4096 + q*512);
    int sel2 = 0;
    for (int kc2 = 0; kc2 < 4; ++kc2) {
        if (kc2 + 1 < 4) {
            #pragma unroll
            for (int q = 0; q < 8; q++)
                async16(Bg2 + (size_t)q*8*256 + (kc2+1)*64,
                        B2s + (sel2^1)*BBUF + wave*4096 + q*512);
            asm volatile("s_waitcnt vmcnt(8)" ::: "memory");
        } else {
            asm volatile("s_waitcnt vmcnt(0)" ::: "memory");
        }
        __builtin_amdgcn_s_barrier();
        __builtin_amdgcn_sched_barrier(0);
        const unsigned short* Bb2 = B2s + sel2*BBUF;
        #pragma unroll
        for (int kh2 = 0; kh2 < 2; kh2++) {
            const int off = off0 ^ (kh2 * 32);
            short8 a = *(const short8*)(Us + fr * 256 + kc2*64 + off);
            short8 b[4];
            #pragma unroll
            for (int j = 0; j < 4; j++)
                b[j] = *(const short8*)(Bb2 + (wc + j*16 + fr) * 64 + off);
            #pragma unroll
            for (int j = 0; j < 4; j++)
                acc2[j] = __builtin_amdgcn_mfma_f32_16x16x32_bf16(
                    a, b[j], acc2[j], 0, 0, 0);
        }
        __builtin_amdgcn_s_barrier();
        sel2 ^= 1;
    }
    // hwT8 fp8 store, wave-transposed to 16B/lane (4x fewer transactions).
    unsigned pk[4];
    #pragma unroll
    for (int j = 0; j < 4; j++)
        pk[j] = (unsigned)f2e4m3(acc2[j][0] * HWSCALE)
              | ((unsigned)f2e4m3(acc2[j][1] * HWSCALE) << 8)
              | ((unsigned)f2e4m3(acc2[j][2] * HWSCALE) << 16)
              | ((unsigned)f2e4m3(acc2[j][3] * HWSCALE) << 24);
    unsigned o0 = 0, o1 = 0, o2 = 0, o3 = 0;
    #pragma unroll
    for (int d = 0; d < 4; d++) {
        unsigned g0 = __shfl(pk[d],  0 + fr, 64);
        unsigned g1 = __shfl(pk[d], 16 + fr, 64);
        unsigned g2 = __shfl(pk[d], 32 + fr, 64);
        unsigned g3 = __shfl(pk[d], 48 + fr, 64);
        if (fq == d) { o0 = g0; o1 = g1; o2 = g2; o3 = g3; }
    }
    {
        int cg = half*256 + wc + fq*16 + fr;          // lane-unique col
        uint4 o; o.x = o0; o.y = o1; o.z = o2; o.w = o3;   // n = row0..row0+15
        *(uint4*)(hwT8 + (size_t)cg * NN + row0) = o;
    }

    // x_{t+1} prefetch into HCb (half==0 blocks: 256 x 256 threads = 65536)
    if (half == 0 && t + 1 < TT) {
        int gid = (bid >> 1) * 256 + tid;
        int n = gid >> 4, d = gid & 15;
        HCb[(size_t)n * KG + 256 + d] = f2bf(inputs[(size_t)n * TD + (t + 1) * DD + d]);
    }
}

extern "C" void kernel_launch(void* const* d_in, const int* in_sizes, int n_in,
                              void* d_out_v, int out_size, void* d_ws, size_t ws_size,
                              hipStream_t stream)
{
    const float* inputs = (const float*)d_in[0];
    const float* A      = (const float*)d_in[1];
    const float* kern   = (const float*)d_in[2];
    const float* rk     = (const float*)d_in[3];
    const float* lb     = (const float*)d_in[4];
    const float* Wgh    = (const float*)d_in[5];
    const float* bgh    = (const float*)d_in[6];
    const float* Wgc    = (const float*)d_in[7];
    const float* bgc    = (const float*)d_in[8];
    const float* Whc    = (const float*)d_in[9];
    const float* Whp    = (const float*)d_in[10];
    const float* bh     = (const float*)d_in[11];
    const float* Wcc    = (const float*)d_in[12];
    const float* Wcp    = (const float*)d_in[13];
    const float* bc     = (const float*)d_in[14];
    const float* Wout   = (const float*)d_in[15];
    const float* bout   = (const float*)d_in[16];
    float* d_out = (float*)d_out_v;

    char* ws = (char*)d_ws;
    size_t off = 0;
    auto alloc = [&](size_t bytes) {
        char* p = ws + off;
        off += (bytes + 255) & ~(size_t)255;
        return p;
    };
    unsigned char*  A8    = (unsigned char*) alloc((size_t)NN * NN);           // 16 MB
    unsigned char*  hwT8  = (unsigned char*) alloc((size_t)512 * NN);          // 2 MB
    unsigned short* HCb   = (unsigned short*)alloc((size_t)NN * KG * 2);       // 2.5 MB
    unsigned short* WzTb  = (unsigned short*)alloc((size_t)1024 * KG * 2);
    unsigned short* WgT   = (unsigned short*)alloc((size_t)512 * 256 * 2);
    unsigned short* WU    = (unsigned short*)alloc((size_t)512 * 512 * 2);
    float*          biasg = (float*)         alloc(1024 * 4);
    unsigned short* LHS3  = (unsigned short*)alloc((size_t)NN * 1024 * 2);     // 8 MB
    float*          Cst   = (float*)         alloc((size_t)NN * HH * 4);       // 4 MB
    (void)in_sizes; (void)n_in; (void)out_size; (void)ws_size;

    k_prep_a<<<2048, 256, 0, stream>>>(A, A8);
    k_prep_w<<<256, 256, 0, stream>>>(Wgh, Wgc, rk, kern, lb,
                                      Whc, Whp, Wcc, Wcp, WzTb, WgT, WU, biasg);
    k_prep_s<<<512, 256, 0, stream>>>(inputs, HCb, hwT8, Cst);

    for (int t = 0; t < TT; t++) {
        k_a<<<1024, 256, 0, stream>>>(A8, hwT8, bgh, bgc,
                                      HCb, WzTb, biasg, Cst, LHS3);
        k_uf<<<512, 256, 0, stream>>>(LHS3, WU, WgT, bh, bc, Wout, bout,
                                      Cst, HCb, hwT8, d_out, inputs, t);
    }
}